// Round 14
// baseline (783.347 us; speedup 1.0000x reference)
//
#include <hip/hip_runtime.h>
#include <math.h>

#define B_  2
#define W_  2048
#define C_  1024
#define NH_ 16
#define KD_ 64

// ---------------------------------------------------------------------------
// XOR-swizzled 64x64 fp32 tile in flat float[4096].
// float4 chunk q of row r lives at slot q ^ ((r>>2)&7).
// ---------------------------------------------------------------------------
__device__ __forceinline__ int sw(int r, int c) {   // c must be 0 mod 4
    return (r << 6) + ((((c >> 2) ^ ((r >> 2) & 7)) << 2) | (c & 3));
}

__device__ __forceinline__ void stage64s(const float* __restrict__ src,
                                         float* dst, int tid) {
#pragma unroll
    for (int q = 0; q < 4; ++q) {
        int idx = tid + (q << 8);        // float4 index 0..1023
        int r   = idx >> 4;
        int c   = (idx & 15) << 2;
        *(float4*)&dst[sw(r, c)] = *(const float4*)(src + (idx << 2));
    }
}

// Padded staging used by qgen (patterns there are conflict-free already)
__device__ __forceinline__ void stage64(const float* __restrict__ src,
                                        float (*dst)[68], int tid) {
#pragma unroll
    for (int q = 0; q < 4; ++q) {
        int idx = tid + (q << 8);
        int e   = idx << 2;
        int r   = e >> 6;
        int c   = e & 63;
        *(float4*)&dst[r][c] = *(const float4*)(src + e);
    }
}

// ---------------------------------------------------------------------------
// GEMM NT:  C[m, c] = sum_k A[m,k] * Bw[c,k] + bias[c]
// v12: double-buffered panels + register prefetch + ONE barrier per panel
// (the attn v4/v9 pipeline pattern). Old structure exposed the ~200cy L2
// load latency 64x per block (load -> barrier -> write -> barrier -> FMA).
// Now: prefetch panel p+1 at top (hidden under 256 FMAs), deposit after
// compute, single barrier. FMA order per output unchanged (k ascending)
// -> bitwise-identical results. launch_bounds(256,4): LDS 17KB, ~90 regs.
// ---------------------------------------------------------------------------
template<int OUT_P_LAYOUT>
__global__ __launch_bounds__(256, 4)
void gemm_nt(const float* __restrict__ A, const float* __restrict__ Bw,
             const float* __restrict__ bias, float* __restrict__ Cout)
{
    __shared__ float As[2][16][68];
    __shared__ float Bs[2][16][68];
    const int tid = threadIdx.x;
    const int tx  = tid & 15, ty = tid >> 4;
    const int m0  = blockIdx.x << 6;
    const int n0  = blockIdx.y << 6;
    const int lrow = tid >> 2;
    const int lkq  = (tid & 3) << 2;
    const float* Ap = A  + (size_t)(m0 + lrow) * C_ + lkq;
    const float* Bp = Bw + (size_t)(n0 + lrow) * C_ + lkq;

    // Prologue: panel 0 -> buf 0.
    float4 av = *(const float4*)(Ap);
    float4 bv = *(const float4*)(Bp);
    As[0][lkq+0][lrow] = av.x; As[0][lkq+1][lrow] = av.y;
    As[0][lkq+2][lrow] = av.z; As[0][lkq+3][lrow] = av.w;
    Bs[0][lkq+0][lrow] = bv.x; Bs[0][lkq+1][lrow] = bv.y;
    Bs[0][lkq+2][lrow] = bv.z; Bs[0][lkq+3][lrow] = bv.w;
    __syncthreads();

    float acc[4][4] = {};
    for (int p = 0; p < 64; ++p) {
        const int cur = p & 1;

        // Prefetch panel p+1 (consumed after the FMA block).
        if (p < 63) {
            av = *(const float4*)(Ap + ((p + 1) << 4));
            bv = *(const float4*)(Bp + ((p + 1) << 4));
        }

#pragma unroll
        for (int kk = 0; kk < 16; ++kk) {
            float4 a4 = *(const float4*)&As[cur][kk][ty << 2];
            float4 b4 = *(const float4*)&Bs[cur][kk][tx << 2];
            float am[4] = {a4.x, a4.y, a4.z, a4.w};
            float bm[4] = {b4.x, b4.y, b4.z, b4.w};
#pragma unroll
            for (int i = 0; i < 4; ++i)
#pragma unroll
                for (int j = 0; j < 4; ++j)
                    acc[i][j] = fmaf(am[i], bm[j], acc[i][j]);
        }

        // Deposit panel p+1 into the other buffer (readers of it finished
        // before the barrier that ended iter p-1).
        if (p < 63) {
            As[cur^1][lkq+0][lrow] = av.x; As[cur^1][lkq+1][lrow] = av.y;
            As[cur^1][lkq+2][lrow] = av.z; As[cur^1][lkq+3][lrow] = av.w;
            Bs[cur^1][lkq+0][lrow] = bv.x; Bs[cur^1][lkq+1][lrow] = bv.y;
            Bs[cur^1][lkq+2][lrow] = bv.z; Bs[cur^1][lkq+3][lrow] = bv.w;
        }
        __syncthreads();   // publishes panel p+1; retires reads of buf cur
    }

    const int gc = n0 + (tx << 2);
    float4 bb = *(const float4*)&bias[gc];
#pragma unroll
    for (int i = 0; i < 4; ++i) {
        int gm = m0 + (ty << 2) + i;
        float4 o;
        o.x = acc[i][0] + bb.x;
        o.y = acc[i][1] + bb.y;
        o.z = acc[i][2] + bb.z;
        o.w = acc[i][3] + bb.w;
        if (OUT_P_LAYOUT) {
            int b = gm >> 11;
            int w = gm & 2047;
            int n = gc >> 6;
            int k = gc & 63;
            *(float4*)(Cout + (((size_t)(b * NH_ + n) * W_ + w) * KD_ + k)) = o;
        } else {
            *(float4*)(Cout + (size_t)gm * C_ + gc) = o;
        }
    }
}

// ---------------------------------------------------------------------------
// metric_part: partial M1[k][l] = sum_{w in chunk} p[bn][w][k] * g[n][w][l]
// ---------------------------------------------------------------------------
__global__ __launch_bounds__(256, 2)
void metric_part(const float* __restrict__ p, const float* __restrict__ g,
                 float* __restrict__ part)
{
    __shared__ float Ps[32][68];
    __shared__ float Gs[32][68];
    const int ch  = blockIdx.x;
    const int bn  = blockIdx.y;
    const int n   = bn & (NH_ - 1);
    const int tid = threadIdx.x;
    const int tx  = tid & 15, ty = tid >> 4;
    const float* pb = p + (size_t)bn * W_ * KD_ + (size_t)(ch << 8) * KD_;
    const float* gb = g + (size_t)n  * W_ * KD_ + (size_t)(ch << 8) * KD_;

    float acc[4][4] = {};
    for (int w0 = 0; w0 < 256; w0 += 32) {
        __syncthreads();
#pragma unroll
        for (int q = 0; q < 2; ++q) {
            int idx = tid + (q << 8);
            int e   = idx << 2;
            int r   = e >> 6;
            int c   = e & 63;
            *(float4*)&Ps[r][c] = *(const float4*)(pb + (size_t)(w0 + r) * KD_ + c);
            *(float4*)&Gs[r][c] = *(const float4*)(gb + (size_t)(w0 + r) * KD_ + c);
        }
        __syncthreads();
#pragma unroll 8
        for (int w = 0; w < 32; ++w) {
            float4 a4 = *(const float4*)&Ps[w][ty << 2];
            float4 b4 = *(const float4*)&Gs[w][tx << 2];
            float am[4] = {a4.x, a4.y, a4.z, a4.w};
            float bm[4] = {b4.x, b4.y, b4.z, b4.w};
#pragma unroll
            for (int i = 0; i < 4; ++i)
#pragma unroll
                for (int j = 0; j < 4; ++j)
                    acc[i][j] = fmaf(am[i], bm[j], acc[i][j]);
        }
    }

    float* ob = part + (size_t)(bn * 8 + ch) * KD_ * KD_;
#pragma unroll
    for (int i = 0; i < 4; ++i) {
        float4 o; o.x = acc[i][0]; o.y = acc[i][1]; o.z = acc[i][2]; o.w = acc[i][3];
        *(float4*)(ob + ((ty << 2) + i) * KD_ + (tx << 2)) = o;
    }
}

// ---------------------------------------------------------------------------
// metric_reduce: M1 = tril(sum_ch part);  M2 = M1 @ M1^T.  Grid: 32 blocks.
// ---------------------------------------------------------------------------
__global__ __launch_bounds__(256, 2)
void metric_reduce(const float* __restrict__ part, float* __restrict__ m2)
{
    __shared__ float M1s[64][68];
    const int bn  = blockIdx.x;
    const int tid = threadIdx.x;
    const int tx  = tid & 15, ty = tid >> 4;
    const float* pb = part + (size_t)bn * 8 * KD_ * KD_;

#pragma unroll
    for (int v = 0; v < 4; ++v) {
        int f = tid + (v << 8);          // float4 index 0..1023
        int e = f << 2;
        float4 s = *(const float4*)(pb + e);
#pragma unroll
        for (int c = 1; c < 8; ++c) {
            float4 t = *(const float4*)(pb + c * 4096 + e);
            s.x += t.x; s.y += t.y; s.z += t.z; s.w += t.w;
        }
        int k = e >> 6, l = e & 63;
        if (l + 0 > k) s.x = 0.f;
        if (l + 1 > k) s.y = 0.f;
        if (l + 2 > k) s.z = 0.f;
        if (l + 3 > k) s.w = 0.f;
        *(float4*)&M1s[k][l] = s;
    }
    __syncthreads();

    float a2[4][4] = {};
#pragma unroll
    for (int jq = 0; jq < 64; jq += 4) {
        float4 av[4], bv[4];
#pragma unroll
        for (int i = 0; i < 4; ++i) av[i] = *(const float4*)&M1s[(ty << 2) + i][jq];
#pragma unroll
        for (int j = 0; j < 4; ++j) bv[j] = *(const float4*)&M1s[(tx << 2) + j][jq];
#pragma unroll
        for (int i = 0; i < 4; ++i)
#pragma unroll
            for (int j = 0; j < 4; ++j)
                a2[i][j] += av[i].x * bv[j].x + av[i].y * bv[j].y +
                            av[i].z * bv[j].z + av[i].w * bv[j].w;
    }

    float* ob = m2 + (size_t)bn * KD_ * KD_;
#pragma unroll
    for (int i = 0; i < 4; ++i) {
        float4 o; o.x = a2[i][0]; o.y = a2[i][1]; o.z = a2[i][2]; o.w = a2[i][3];
        *(float4*)(ob + ((ty << 2) + i) * KD_ + (tx << 2)) = o;
    }
}

// ---------------------------------------------------------------------------
// Q[bn][w][l] = (1/8) * sum_k p[bn][w][k] * M2[bn][k][l]
// ---------------------------------------------------------------------------
__global__ __launch_bounds__(256, 2)
void qgen_k(const float* __restrict__ p, const float* __restrict__ m2,
            float* __restrict__ qout)
{
    __shared__ float Pt[64][68];
    __shared__ float Ms[64][68];
    const int bn  = blockIdx.y;
    const int w0  = blockIdx.x << 6;
    const int tid = threadIdx.x;
    const int tx  = tid & 15, ty = tid >> 4;
    const float* pb = p  + (size_t)bn * W_ * KD_ + (size_t)w0 * KD_;
    const float* mb = m2 + (size_t)bn * KD_ * KD_;

    stage64(pb, Pt, tid);
    stage64(mb, Ms, tid);
    __syncthreads();

    float acc[4][4] = {};
#pragma unroll
    for (int kq = 0; kq < 64; kq += 4) {
        float4 av[4];
        float  bm[4][4];
#pragma unroll
        for (int i = 0; i < 4; ++i) av[i] = *(const float4*)&Pt[(ty << 2) + i][kq];
#pragma unroll
        for (int kk = 0; kk < 4; ++kk) {
            float4 t = *(const float4*)&Ms[kq + kk][tx << 2];
            bm[kk][0] = t.x; bm[kk][1] = t.y; bm[kk][2] = t.z; bm[kk][3] = t.w;
        }
#pragma unroll
        for (int i = 0; i < 4; ++i) {
            float am[4] = {av[i].x, av[i].y, av[i].z, av[i].w};
#pragma unroll
            for (int j = 0; j < 4; ++j)
                acc[i][j] = fmaf(am[0], bm[0][j],
                            fmaf(am[1], bm[1][j],
                            fmaf(am[2], bm[2][j],
                            fmaf(am[3], bm[3][j], acc[i][j]))));
        }
    }

    float* ob = qout + (size_t)bn * W_ * KD_ + (size_t)w0 * KD_;
#pragma unroll
    for (int i = 0; i < 4; ++i) {
        float4 o;
        o.x = acc[i][0] * 0.125f; o.y = acc[i][1] * 0.125f;
        o.z = acc[i][2] * 0.125f; o.w = acc[i][3] * 0.125f;
        *(float4*)(ob + ((ty << 2) + i) * KD_ + (tx << 2)) = o;
    }
}

// ---------------------------------------------------------------------------
// Causal flash attention per (b,n): q = Q (pre-scaled), k = v = P.
// v11 (unchanged): QBLK=32, conflict-free row map ROW(ty,i) =
// ((ty&3)<<3)+((ty>>2)<<1)+i, 48KB LDS / 3 blocks/CU, single barrier,
// prefetch K(j0+1) -> deposit before PV (liveness shape), setprio.
// Verified: 430us, VALU 54%, conflicts 3.46e7, absmax 0.0234375.
// ---------------------------------------------------------------------------
__global__ __launch_bounds__(256, 3)
void attn_k(const float* __restrict__ qg, const float* __restrict__ p,
            float* __restrict__ nud)
{
    __shared__ float Qs[2048];       // 32 x 64
    __shared__ float Ks[2][4096];    // 2 x (64 x 64)
    __shared__ float Es[2048];       // 32 x 64
    const int bid  = blockIdx.x;
    const int bn   = bid & 31;
    const int t    = 63 - (bid >> 5);     // 32-row q-tile, heavy first
    const int jmax = t >> 1;
    const int b    = bn >> 4, n = bn & 15;
    const int tid  = threadIdx.x;
    const int tx   = tid & 15, ty = tid >> 4;
    const int rbase = ((ty & 3) << 3) + ((ty >> 2) << 1);  // rows rbase, rbase+1
    const int roff = (t & 1) << 5;              // diagonal offset in last chunk
    const float* qb = qg + (size_t)bn * W_ * KD_ + (size_t)(t << 5) * KD_;
    const float* kb = p  + (size_t)bn * W_ * KD_;

    // Prologue: stage Q (32x64, 2 float4/thread) and K chunk 0.
#pragma unroll
    for (int q = 0; q < 2; ++q) {
        int idx = tid + (q << 8);
        int r = idx >> 4, c = (idx & 15) << 2;
        *(float4*)&Qs[sw(r, c)] = *(const float4*)(qb + (idx << 2));
    }
    stage64s(kb, Ks[0], tid);
    __syncthreads();

    float acc[2][4] = {};
    float mi[2], li[2];
#pragma unroll
    for (int i = 0; i < 2; ++i) { mi[i] = -INFINITY; li[i] = 0.f; }

    float4 ld[4];                        // in-flight K(j0+1) staging registers

    for (int j0 = 0; j0 <= jmax; ++j0) {
        const int cur = j0 & 1;
        const float* Kc = Ks[cur];

        // Issue next K chunk's global loads NOW (deposited after softmax).
        if (j0 < jmax) {
            const float* nx = kb + (size_t)((j0 + 1) << 6) * KD_;
#pragma unroll
            for (int q = 0; q < 4; ++q)
                ld[q] = *(const float4*)(nx + ((tid + (q << 8)) << 2));
        }

        // S = Qs @ Kc^T
        float s[2][4] = {};
        __builtin_amdgcn_s_setprio(1);
#pragma unroll
        for (int kq = 0; kq < 16; ++kq) {
            float4 av[2], bv[4];
#pragma unroll
            for (int i = 0; i < 2; ++i)
                av[i] = *(const float4*)&Qs[sw(rbase + i, kq << 2)];
#pragma unroll
            for (int j = 0; j < 4; ++j)
                bv[j] = *(const float4*)&Kc[sw((tx << 2) + j, kq << 2)];
#pragma unroll
            for (int i = 0; i < 2; ++i)
#pragma unroll
                for (int j = 0; j < 4; ++j)
                    s[i][j] = fmaf(av[i].x, bv[j].x,
                              fmaf(av[i].y, bv[j].y,
                              fmaf(av[i].z, bv[j].z,
                              fmaf(av[i].w, bv[j].w, s[i][j]))));
        }
        __builtin_amdgcn_s_setprio(0);

        if (j0 == jmax) {
#pragma unroll
            for (int i = 0; i < 2; ++i)
#pragma unroll
                for (int j = 0; j < 4; ++j)
                    if (((tx << 2) + j) > (roff + rbase + i)) s[i][j] = -INFINITY;
        }

        float mnew[2], al[2];
#pragma unroll
        for (int i = 0; i < 2; ++i) {
            float rm = fmaxf(fmaxf(s[i][0], s[i][1]), fmaxf(s[i][2], s[i][3]));
            rm = fmaxf(rm, __shfl_xor(rm, 1, 16));
            rm = fmaxf(rm, __shfl_xor(rm, 2, 16));
            rm = fmaxf(rm, __shfl_xor(rm, 4, 16));
            rm = fmaxf(rm, __shfl_xor(rm, 8, 16));
            mnew[i] = fmaxf(mi[i], rm);
        }
#pragma unroll
        for (int i = 0; i < 2; ++i) {
#pragma unroll
            for (int j = 0; j < 4; ++j) s[i][j] = __expf(s[i][j] - mnew[i]);
            float rs = s[i][0] + s[i][1] + s[i][2] + s[i][3];
            rs += __shfl_xor(rs, 1, 16);
            rs += __shfl_xor(rs, 2, 16);
            rs += __shfl_xor(rs, 4, 16);
            rs += __shfl_xor(rs, 8, 16);
            al[i] = __expf(mi[i] - mnew[i]);
            li[i] = li[i] * al[i] + rs;
            mi[i] = mnew[i];
        }

        // Es write — wave-private rows; no barrier needed before PV
        // (validated by v8/v9/v10/v11).
#pragma unroll
        for (int i = 0; i < 2; ++i) {
            float4 e; e.x = s[i][0]; e.y = s[i][1]; e.z = s[i][2]; e.w = s[i][3];
            *(float4*)&Es[sw(rbase + i, tx << 2)] = e;
#pragma unroll
            for (int j = 0; j < 4; ++j) acc[i][j] *= al[i];
        }

        // Deposit prefetched K(j0+1) NOW — kills ld[] before PV (liveness).
        if (j0 < jmax) {
            float* Kn = (float*)Ks[cur ^ 1];
#pragma unroll
            for (int q = 0; q < 4; ++q) {
                int idx = tid + (q << 8);
                *(float4*)&Kn[sw(idx >> 4, (idx & 15) << 2)] = ld[q];
            }
        }

        // O += Es @ Kc   (V = K chunk)
        __builtin_amdgcn_s_setprio(1);
#pragma unroll
        for (int jq = 0; jq < 64; jq += 4) {
            float4 av[2];
            float  vm[4][4];
#pragma unroll
            for (int i = 0; i < 2; ++i)
                av[i] = *(const float4*)&Es[sw(rbase + i, jq)];
#pragma unroll
            for (int kk = 0; kk < 4; ++kk) {
                float4 tv = *(const float4*)&Kc[sw(jq + kk, tx << 2)];
                vm[kk][0] = tv.x; vm[kk][1] = tv.y; vm[kk][2] = tv.z; vm[kk][3] = tv.w;
            }
#pragma unroll
            for (int i = 0; i < 2; ++i) {
                float am[4] = {av[i].x, av[i].y, av[i].z, av[i].w};
#pragma unroll
                for (int c = 0; c < 4; ++c)
                    acc[i][c] = fmaf(am[0], vm[0][c],
                                fmaf(am[1], vm[1][c],
                                fmaf(am[2], vm[2][c],
                                fmaf(am[3], vm[3][c], acc[i][c]))));
            }
        }
        __builtin_amdgcn_s_setprio(0);

        __syncthreads();   // single barrier: publishes Kn, retires Kc/Es reads
    }

    const int wrow = t << 5;
#pragma unroll
    for (int i = 0; i < 2; ++i) {
        float inv = 1.f / li[i];
        float4 o;
        o.x = acc[i][0] * inv; o.y = acc[i][1] * inv;
        o.z = acc[i][2] * inv; o.w = acc[i][3] * inv;
        size_t row = (size_t)(b * W_ + wrow + rbase + i);
        *(float4*)(nud + row * C_ + (n << 6) + (tx << 2)) = o;
    }
}

// ---------------------------------------------------------------------------
extern "C" void kernel_launch(void* const* d_in, const int* in_sizes, int n_in,
                              void* d_out, int out_size, void* d_ws, size_t ws_size,
                              hipStream_t stream)
{
    (void)in_sizes; (void)n_in; (void)out_size; (void)ws_size;
    const float* X  = (const float*)d_in[0];   // (2,2048,1024)
    const float* Wp = (const float*)d_in[1];   // (1024,1024)
    const float* bp = (const float*)d_in[2];   // (1024,)
    const float* G  = (const float*)d_in[3];   // (1,16,2048,64)
    const float* Wm = (const float*)d_in[4];   // (1024,1024)
    const float* bm = (const float*)d_in[5];   // (1024,)
    float* out = (float*)d_out;                // (2,2048,1024)
    float* ws  = (float*)d_ws;

    float* Pbuf = ws;                // 4194304 floats  [bn][w][k]
    float* Qbuf = ws + 4194304;      // 4194304 floats  [bn][w][k]
    float* M2   = ws + 8388608;      // 131072 floats   [bn][k][l]
    float* Nud  = ws + 8519680;      // 4194304 floats  [b*W+w][c]
    // metric partials overlay Qbuf (dead until qgen_k writes it):
    float* Part = Qbuf;              // 32*8*4096 = 1048576 floats

    dim3 blk(256);
    gemm_nt<1>   <<<dim3(64, 16), blk, 0, stream>>>(X, Wp, bp, Pbuf);
    metric_part  <<<dim3(8, 32),  blk, 0, stream>>>(Pbuf, G, Part);
    metric_reduce<<<dim3(32),     blk, 0, stream>>>(Part, M2);
    qgen_k       <<<dim3(32, 32), blk, 0, stream>>>(Pbuf, M2, Qbuf);
    attn_k       <<<dim3(2048),   blk, 0, stream>>>(Qbuf, Pbuf, Nud);
    gemm_nt<0>   <<<dim3(64, 16), blk, 0, stream>>>(Nud, Wm, bm, out);
}

// Round 15
// 722.943 us; speedup vs baseline: 1.0836x; 1.0836x over previous
//
#include <hip/hip_runtime.h>
#include <math.h>

#define B_  2
#define W_  2048
#define C_  1024
#define NH_ 16
#define KD_ 64

// ---------------------------------------------------------------------------
// XOR-swizzled 64x64 fp32 tile in flat float[4096].
// float4 chunk q of row r lives at slot q ^ ((r>>2)&7).
// ---------------------------------------------------------------------------
__device__ __forceinline__ int sw(int r, int c) {   // c must be 0 mod 4
    return (r << 6) + ((((c >> 2) ^ ((r >> 2) & 7)) << 2) | (c & 3));
}

__device__ __forceinline__ void stage64s(const float* __restrict__ src,
                                         float* dst, int tid) {
#pragma unroll
    for (int q = 0; q < 4; ++q) {
        int idx = tid + (q << 8);        // float4 index 0..1023
        int r   = idx >> 4;
        int c   = (idx & 15) << 2;
        *(float4*)&dst[sw(r, c)] = *(const float4*)(src + (idx << 2));
    }
}

// Padded staging used by qgen (patterns there are conflict-free already)
__device__ __forceinline__ void stage64(const float* __restrict__ src,
                                        float (*dst)[68], int tid) {
#pragma unroll
    for (int q = 0; q < 4; ++q) {
        int idx = tid + (q << 8);
        int e   = idx << 2;
        int r   = e >> 6;
        int c   = e & 63;
        *(float4*)&dst[r][c] = *(const float4*)(src + e);
    }
}

// ---------------------------------------------------------------------------
// GEMM NT:  C[m, c] = sum_k A[m,k] * Bw[c,k] + bias[c]
// REVERTED to the original (r13/762us-verified) structure: v12's
// single-barrier double-buffer variant measured +25us on the "others"
// budget (vmcnt drains at the ds_write right before the barrier, so load
// latency wasn't hidden; bigger LDS + tighter launch_bounds cost the
// occupancy slack that was covering the old pattern via TLP).
// ---------------------------------------------------------------------------
template<int OUT_P_LAYOUT>
__global__ __launch_bounds__(256, 2)
void gemm_nt(const float* __restrict__ A, const float* __restrict__ Bw,
             const float* __restrict__ bias, float* __restrict__ Cout)
{
    __shared__ float As[16][68];
    __shared__ float Bs[16][68];
    const int tid = threadIdx.x;
    const int tx  = tid & 15, ty = tid >> 4;
    const int m0  = blockIdx.x << 6;
    const int n0  = blockIdx.y << 6;
    const int lrow = tid >> 2;
    const int lkq  = (tid & 3) << 2;
    const float* Ap = A  + (size_t)(m0 + lrow) * C_ + lkq;
    const float* Bp = Bw + (size_t)(n0 + lrow) * C_ + lkq;

    float acc[4][4] = {};
    for (int k0 = 0; k0 < C_; k0 += 16) {
        float4 av = *(const float4*)(Ap + k0);
        float4 bv = *(const float4*)(Bp + k0);
        __syncthreads();
        As[lkq+0][lrow] = av.x; As[lkq+1][lrow] = av.y;
        As[lkq+2][lrow] = av.z; As[lkq+3][lrow] = av.w;
        Bs[lkq+0][lrow] = bv.x; Bs[lkq+1][lrow] = bv.y;
        Bs[lkq+2][lrow] = bv.z; Bs[lkq+3][lrow] = bv.w;
        __syncthreads();
#pragma unroll
        for (int kk = 0; kk < 16; ++kk) {
            float4 a4 = *(const float4*)&As[kk][ty << 2];
            float4 b4 = *(const float4*)&Bs[kk][tx << 2];
            float am[4] = {a4.x, a4.y, a4.z, a4.w};
            float bm[4] = {b4.x, b4.y, b4.z, b4.w};
#pragma unroll
            for (int i = 0; i < 4; ++i)
#pragma unroll
                for (int j = 0; j < 4; ++j)
                    acc[i][j] = fmaf(am[i], bm[j], acc[i][j]);
        }
    }

    const int gc = n0 + (tx << 2);
    float4 bb = *(const float4*)&bias[gc];
#pragma unroll
    for (int i = 0; i < 4; ++i) {
        int gm = m0 + (ty << 2) + i;
        float4 o;
        o.x = acc[i][0] + bb.x;
        o.y = acc[i][1] + bb.y;
        o.z = acc[i][2] + bb.z;
        o.w = acc[i][3] + bb.w;
        if (OUT_P_LAYOUT) {
            int b = gm >> 11;
            int w = gm & 2047;
            int n = gc >> 6;
            int k = gc & 63;
            *(float4*)(Cout + (((size_t)(b * NH_ + n) * W_ + w) * KD_ + k)) = o;
        } else {
            *(float4*)(Cout + (size_t)gm * C_ + gc) = o;
        }
    }
}

// ---------------------------------------------------------------------------
// metric_part: partial M1[k][l] = sum_{w in chunk} p[bn][w][k] * g[n][w][l]
// ---------------------------------------------------------------------------
__global__ __launch_bounds__(256, 2)
void metric_part(const float* __restrict__ p, const float* __restrict__ g,
                 float* __restrict__ part)
{
    __shared__ float Ps[32][68];
    __shared__ float Gs[32][68];
    const int ch  = blockIdx.x;
    const int bn  = blockIdx.y;
    const int n   = bn & (NH_ - 1);
    const int tid = threadIdx.x;
    const int tx  = tid & 15, ty = tid >> 4;
    const float* pb = p + (size_t)bn * W_ * KD_ + (size_t)(ch << 8) * KD_;
    const float* gb = g + (size_t)n  * W_ * KD_ + (size_t)(ch << 8) * KD_;

    float acc[4][4] = {};
    for (int w0 = 0; w0 < 256; w0 += 32) {
        __syncthreads();
#pragma unroll
        for (int q = 0; q < 2; ++q) {
            int idx = tid + (q << 8);
            int e   = idx << 2;
            int r   = e >> 6;
            int c   = e & 63;
            *(float4*)&Ps[r][c] = *(const float4*)(pb + (size_t)(w0 + r) * KD_ + c);
            *(float4*)&Gs[r][c] = *(const float4*)(gb + (size_t)(w0 + r) * KD_ + c);
        }
        __syncthreads();
#pragma unroll 8
        for (int w = 0; w < 32; ++w) {
            float4 a4 = *(const float4*)&Ps[w][ty << 2];
            float4 b4 = *(const float4*)&Gs[w][tx << 2];
            float am[4] = {a4.x, a4.y, a4.z, a4.w};
            float bm[4] = {b4.x, b4.y, b4.z, b4.w};
#pragma unroll
            for (int i = 0; i < 4; ++i)
#pragma unroll
                for (int j = 0; j < 4; ++j)
                    acc[i][j] = fmaf(am[i], bm[j], acc[i][j]);
        }
    }

    float* ob = part + (size_t)(bn * 8 + ch) * KD_ * KD_;
#pragma unroll
    for (int i = 0; i < 4; ++i) {
        float4 o; o.x = acc[i][0]; o.y = acc[i][1]; o.z = acc[i][2]; o.w = acc[i][3];
        *(float4*)(ob + ((ty << 2) + i) * KD_ + (tx << 2)) = o;
    }
}

// ---------------------------------------------------------------------------
// metric_reduce: M1 = tril(sum_ch part);  M2 = M1 @ M1^T.  Grid: 32 blocks.
// ---------------------------------------------------------------------------
__global__ __launch_bounds__(256, 2)
void metric_reduce(const float* __restrict__ part, float* __restrict__ m2)
{
    __shared__ float M1s[64][68];
    const int bn  = blockIdx.x;
    const int tid = threadIdx.x;
    const int tx  = tid & 15, ty = tid >> 4;
    const float* pb = part + (size_t)bn * 8 * KD_ * KD_;

#pragma unroll
    for (int v = 0; v < 4; ++v) {
        int f = tid + (v << 8);          // float4 index 0..1023
        int e = f << 2;
        float4 s = *(const float4*)(pb + e);
#pragma unroll
        for (int c = 1; c < 8; ++c) {
            float4 t = *(const float4*)(pb + c * 4096 + e);
            s.x += t.x; s.y += t.y; s.z += t.z; s.w += t.w;
        }
        int k = e >> 6, l = e & 63;
        if (l + 0 > k) s.x = 0.f;
        if (l + 1 > k) s.y = 0.f;
        if (l + 2 > k) s.z = 0.f;
        if (l + 3 > k) s.w = 0.f;
        *(float4*)&M1s[k][l] = s;
    }
    __syncthreads();

    float a2[4][4] = {};
#pragma unroll
    for (int jq = 0; jq < 64; jq += 4) {
        float4 av[4], bv[4];
#pragma unroll
        for (int i = 0; i < 4; ++i) av[i] = *(const float4*)&M1s[(ty << 2) + i][jq];
#pragma unroll
        for (int j = 0; j < 4; ++j) bv[j] = *(const float4*)&M1s[(tx << 2) + j][jq];
#pragma unroll
        for (int i = 0; i < 4; ++i)
#pragma unroll
            for (int j = 0; j < 4; ++j)
                a2[i][j] += av[i].x * bv[j].x + av[i].y * bv[j].y +
                            av[i].z * bv[j].z + av[i].w * bv[j].w;
    }

    float* ob = m2 + (size_t)bn * KD_ * KD_;
#pragma unroll
    for (int i = 0; i < 4; ++i) {
        float4 o; o.x = a2[i][0]; o.y = a2[i][1]; o.z = a2[i][2]; o.w = a2[i][3];
        *(float4*)(ob + ((ty << 2) + i) * KD_ + (tx << 2)) = o;
    }
}

// ---------------------------------------------------------------------------
// Q[bn][w][l] = (1/8) * sum_k p[bn][w][k] * M2[bn][k][l]
// ---------------------------------------------------------------------------
__global__ __launch_bounds__(256, 2)
void qgen_k(const float* __restrict__ p, const float* __restrict__ m2,
            float* __restrict__ qout)
{
    __shared__ float Pt[64][68];
    __shared__ float Ms[64][68];
    const int bn  = blockIdx.y;
    const int w0  = blockIdx.x << 6;
    const int tid = threadIdx.x;
    const int tx  = tid & 15, ty = tid >> 4;
    const float* pb = p  + (size_t)bn * W_ * KD_ + (size_t)w0 * KD_;
    const float* mb = m2 + (size_t)bn * KD_ * KD_;

    stage64(pb, Pt, tid);
    stage64(mb, Ms, tid);
    __syncthreads();

    float acc[4][4] = {};
#pragma unroll
    for (int kq = 0; kq < 64; kq += 4) {
        float4 av[4];
        float  bm[4][4];
#pragma unroll
        for (int i = 0; i < 4; ++i) av[i] = *(const float4*)&Pt[(ty << 2) + i][kq];
#pragma unroll
        for (int kk = 0; kk < 4; ++kk) {
            float4 t = *(const float4*)&Ms[kq + kk][tx << 2];
            bm[kk][0] = t.x; bm[kk][1] = t.y; bm[kk][2] = t.z; bm[kk][3] = t.w;
        }
#pragma unroll
        for (int i = 0; i < 4; ++i) {
            float am[4] = {av[i].x, av[i].y, av[i].z, av[i].w};
#pragma unroll
            for (int j = 0; j < 4; ++j)
                acc[i][j] = fmaf(am[0], bm[0][j],
                            fmaf(am[1], bm[1][j],
                            fmaf(am[2], bm[2][j],
                            fmaf(am[3], bm[3][j], acc[i][j]))));
        }
    }

    float* ob = qout + (size_t)bn * W_ * KD_ + (size_t)w0 * KD_;
#pragma unroll
    for (int i = 0; i < 4; ++i) {
        float4 o;
        o.x = acc[i][0] * 0.125f; o.y = acc[i][1] * 0.125f;
        o.z = acc[i][2] * 0.125f; o.w = acc[i][3] * 0.125f;
        *(float4*)(ob + ((ty << 2) + i) * KD_ + (tx << 2)) = o;
    }
}

// ---------------------------------------------------------------------------
// Causal flash attention per (b,n): q = Q (pre-scaled), k = v = P.
// v11 (unchanged, best verified: 430us): QBLK=32, conflict-free row map
// ROW(ty,i) = ((ty&3)<<3)+((ty>>2)<<1)+i, 48KB LDS / 3 blocks/CU, single
// barrier, prefetch K(j0+1) -> deposit before PV (liveness shape), setprio.
// ---------------------------------------------------------------------------
__global__ __launch_bounds__(256, 3)
void attn_k(const float* __restrict__ qg, const float* __restrict__ p,
            float* __restrict__ nud)
{
    __shared__ float Qs[2048];       // 32 x 64
    __shared__ float Ks[2][4096];    // 2 x (64 x 64)
    __shared__ float Es[2048];       // 32 x 64
    const int bid  = blockIdx.x;
    const int bn   = bid & 31;
    const int t    = 63 - (bid >> 5);     // 32-row q-tile, heavy first
    const int jmax = t >> 1;
    const int b    = bn >> 4, n = bn & 15;
    const int tid  = threadIdx.x;
    const int tx   = tid & 15, ty = tid >> 4;
    const int rbase = ((ty & 3) << 3) + ((ty >> 2) << 1);  // rows rbase, rbase+1
    const int roff = (t & 1) << 5;              // diagonal offset in last chunk
    const float* qb = qg + (size_t)bn * W_ * KD_ + (size_t)(t << 5) * KD_;
    const float* kb = p  + (size_t)bn * W_ * KD_;

    // Prologue: stage Q (32x64, 2 float4/thread) and K chunk 0.
#pragma unroll
    for (int q = 0; q < 2; ++q) {
        int idx = tid + (q << 8);
        int r = idx >> 4, c = (idx & 15) << 2;
        *(float4*)&Qs[sw(r, c)] = *(const float4*)(qb + (idx << 2));
    }
    stage64s(kb, Ks[0], tid);
    __syncthreads();

    float acc[2][4] = {};
    float mi[2], li[2];
#pragma unroll
    for (int i = 0; i < 2; ++i) { mi[i] = -INFINITY; li[i] = 0.f; }

    float4 ld[4];                        // in-flight K(j0+1) staging registers

    for (int j0 = 0; j0 <= jmax; ++j0) {
        const int cur = j0 & 1;
        const float* Kc = Ks[cur];

        // Issue next K chunk's global loads NOW (deposited after softmax).
        if (j0 < jmax) {
            const float* nx = kb + (size_t)((j0 + 1) << 6) * KD_;
#pragma unroll
            for (int q = 0; q < 4; ++q)
                ld[q] = *(const float4*)(nx + ((tid + (q << 8)) << 2));
        }

        // S = Qs @ Kc^T
        float s[2][4] = {};
        __builtin_amdgcn_s_setprio(1);
#pragma unroll
        for (int kq = 0; kq < 16; ++kq) {
            float4 av[2], bv[4];
#pragma unroll
            for (int i = 0; i < 2; ++i)
                av[i] = *(const float4*)&Qs[sw(rbase + i, kq << 2)];
#pragma unroll
            for (int j = 0; j < 4; ++j)
                bv[j] = *(const float4*)&Kc[sw((tx << 2) + j, kq << 2)];
#pragma unroll
            for (int i = 0; i < 2; ++i)
#pragma unroll
                for (int j = 0; j < 4; ++j)
                    s[i][j] = fmaf(av[i].x, bv[j].x,
                              fmaf(av[i].y, bv[j].y,
                              fmaf(av[i].z, bv[j].z,
                              fmaf(av[i].w, bv[j].w, s[i][j]))));
        }
        __builtin_amdgcn_s_setprio(0);

        if (j0 == jmax) {
#pragma unroll
            for (int i = 0; i < 2; ++i)
#pragma unroll
                for (int j = 0; j < 4; ++j)
                    if (((tx << 2) + j) > (roff + rbase + i)) s[i][j] = -INFINITY;
        }

        float mnew[2], al[2];
#pragma unroll
        for (int i = 0; i < 2; ++i) {
            float rm = fmaxf(fmaxf(s[i][0], s[i][1]), fmaxf(s[i][2], s[i][3]));
            rm = fmaxf(rm, __shfl_xor(rm, 1, 16));
            rm = fmaxf(rm, __shfl_xor(rm, 2, 16));
            rm = fmaxf(rm, __shfl_xor(rm, 4, 16));
            rm = fmaxf(rm, __shfl_xor(rm, 8, 16));
            mnew[i] = fmaxf(mi[i], rm);
        }
#pragma unroll
        for (int i = 0; i < 2; ++i) {
#pragma unroll
            for (int j = 0; j < 4; ++j) s[i][j] = __expf(s[i][j] - mnew[i]);
            float rs = s[i][0] + s[i][1] + s[i][2] + s[i][3];
            rs += __shfl_xor(rs, 1, 16);
            rs += __shfl_xor(rs, 2, 16);
            rs += __shfl_xor(rs, 4, 16);
            rs += __shfl_xor(rs, 8, 16);
            al[i] = __expf(mi[i] - mnew[i]);
            li[i] = li[i] * al[i] + rs;
            mi[i] = mnew[i];
        }

        // Es write — wave-private rows; no barrier needed before PV
        // (validated by v8/v9/v10/v11).
#pragma unroll
        for (int i = 0; i < 2; ++i) {
            float4 e; e.x = s[i][0]; e.y = s[i][1]; e.z = s[i][2]; e.w = s[i][3];
            *(float4*)&Es[sw(rbase + i, tx << 2)] = e;
#pragma unroll
            for (int j = 0; j < 4; ++j) acc[i][j] *= al[i];
        }

        // Deposit prefetched K(j0+1) NOW — kills ld[] before PV (liveness).
        if (j0 < jmax) {
            float* Kn = (float*)Ks[cur ^ 1];
#pragma unroll
            for (int q = 0; q < 4; ++q) {
                int idx = tid + (q << 8);
                *(float4*)&Kn[sw(idx >> 4, (idx & 15) << 2)] = ld[q];
            }
        }

        // O += Es @ Kc   (V = K chunk)
        __builtin_amdgcn_s_setprio(1);
#pragma unroll
        for (int jq = 0; jq < 64; jq += 4) {
            float4 av[2];
            float  vm[4][4];
#pragma unroll
            for (int i = 0; i < 2; ++i)
                av[i] = *(const float4*)&Es[sw(rbase + i, jq)];
#pragma unroll
            for (int kk = 0; kk < 4; ++kk) {
                float4 tv = *(const float4*)&Kc[sw(jq + kk, tx << 2)];
                vm[kk][0] = tv.x; vm[kk][1] = tv.y; vm[kk][2] = tv.z; vm[kk][3] = tv.w;
            }
#pragma unroll
            for (int i = 0; i < 2; ++i) {
                float am[4] = {av[i].x, av[i].y, av[i].z, av[i].w};
#pragma unroll
                for (int c = 0; c < 4; ++c)
                    acc[i][c] = fmaf(am[0], vm[0][c],
                                fmaf(am[1], vm[1][c],
                                fmaf(am[2], vm[2][c],
                                fmaf(am[3], vm[3][c], acc[i][c]))));
            }
        }
        __builtin_amdgcn_s_setprio(0);

        __syncthreads();   // single barrier: publishes Kn, retires Kc/Es reads
    }

    const int wrow = t << 5;
#pragma unroll
    for (int i = 0; i < 2; ++i) {
        float inv = 1.f / li[i];
        float4 o;
        o.x = acc[i][0] * inv; o.y = acc[i][1] * inv;
        o.z = acc[i][2] * inv; o.w = acc[i][3] * inv;
        size_t row = (size_t)(b * W_ + wrow + rbase + i);
        *(float4*)(nud + row * C_ + (n << 6) + (tx << 2)) = o;
    }
}

// ---------------------------------------------------------------------------
extern "C" void kernel_launch(void* const* d_in, const int* in_sizes, int n_in,
                              void* d_out, int out_size, void* d_ws, size_t ws_size,
                              hipStream_t stream)
{
    (void)in_sizes; (void)n_in; (void)out_size; (void)ws_size;
    const float* X  = (const float*)d_in[0];   // (2,2048,1024)
    const float* Wp = (const float*)d_in[1];   // (1024,1024)
    const float* bp = (const float*)d_in[2];   // (1024,)
    const float* G  = (const float*)d_in[3];   // (1,16,2048,64)
    const float* Wm = (const float*)d_in[4];   // (1024,1024)
    const float* bm = (const float*)d_in[5];   // (1024,)
    float* out = (float*)d_out;                // (2,2048,1024)
    float* ws  = (float*)d_ws;

    float* Pbuf = ws;                // 4194304 floats  [bn][w][k]
    float* Qbuf = ws + 4194304;      // 4194304 floats  [bn][w][k]
    float* M2   = ws + 8388608;      // 131072 floats   [bn][k][l]
    float* Nud  = ws + 8519680;      // 4194304 floats  [b*W+w][c]
    // metric partials overlay Qbuf (dead until qgen_k writes it):
    float* Part = Qbuf;              // 32*8*4096 = 1048576 floats

    dim3 blk(256);
    gemm_nt<1>   <<<dim3(64, 16), blk, 0, stream>>>(X, Wp, bp, Pbuf);
    metric_part  <<<dim3(8, 32),  blk, 0, stream>>>(Pbuf, G, Part);
    metric_reduce<<<dim3(32),     blk, 0, stream>>>(Part, M2);
    qgen_k       <<<dim3(32, 32), blk, 0, stream>>>(Pbuf, M2, Qbuf);
    attn_k       <<<dim3(2048),   blk, 0, stream>>>(Qbuf, Pbuf, Nud);
    gemm_nt<0>   <<<dim3(64, 16), blk, 0, stream>>>(Nud, Wm, bm, out);
}